// Round 3
// baseline (336.199 us; speedup 1.0000x reference)
//
#include <hip/hip_runtime.h>

#define DIMN 2048
#define HDIM 8192

// ws layout (float offsets)
#define WS_XN   0        // 2048  normed x for attention branch
#define WS_Q    2048     // 2048  q vector
#define WS_ATTN 4096     // 2048  attention output accumulator (fp32, atomics)
#define WS_X1   6144     // 2048  x + attn@o_w.T + o_b
#define WS_HN   8192     // 2048  normed x1
#define WS_H    10240    // 8192  gelu(fc1)
#define WS_SC   18432    // 8192  attention scores
#define WS_PR   26624    // 8192  softmax probs

__device__ __forceinline__ float dot4(float4 w, float4 a) {
    return w.x * a.x + w.y * a.y + w.z * a.z + w.w * a.w;
}

__device__ __forceinline__ float waveSum(float v) {
#pragma unroll
    for (int off = 32; off > 0; off >>= 1) v += __shfl_down(v, off, 64);
    return v;  // lane 0 holds the sum
}

// ---------------- kernel 1: xn = rmsnorm(x)*w ; zero attn accumulator ----------------
__global__ void k_rms1(const float* __restrict__ x, const float* __restrict__ w,
                       float* __restrict__ ws) {
    __shared__ float red[5];
    int tid = threadIdx.x;  // 256 threads, 8 elems each
    float4 a = reinterpret_cast<const float4*>(x)[tid * 2];
    float4 b = reinterpret_cast<const float4*>(x)[tid * 2 + 1];
    float ss = a.x * a.x + a.y * a.y + a.z * a.z + a.w * a.w +
               b.x * b.x + b.y * b.y + b.z * b.z + b.w * b.w;
    ss = waveSum(ss);
    int wave = tid >> 6, lane = tid & 63;
    if (lane == 0) red[wave] = ss;
    __syncthreads();
    if (tid == 0) red[4] = rsqrtf((red[0] + red[1] + red[2] + red[3]) / (float)DIMN + 1e-6f);
    __syncthreads();
    float scale = red[4];
    float4 wa = reinterpret_cast<const float4*>(w)[tid * 2];
    float4 wb = reinterpret_cast<const float4*>(w)[tid * 2 + 1];
    float4 o0 = make_float4(a.x * scale * wa.x, a.y * scale * wa.y,
                            a.z * scale * wa.z, a.w * scale * wa.w);
    float4 o1 = make_float4(b.x * scale * wb.x, b.y * scale * wb.y,
                            b.z * scale * wb.z, b.w * scale * wb.w);
    reinterpret_cast<float4*>(ws + WS_XN)[tid * 2] = o0;
    reinterpret_cast<float4*>(ws + WS_XN)[tid * 2 + 1] = o1;
    // zero the fp32 attention accumulator (ws is poisoned 0xAA each call)
    float4 z = make_float4(0.f, 0.f, 0.f, 0.f);
    reinterpret_cast<float4*>(ws + WS_ATTN)[tid * 2] = z;
    reinterpret_cast<float4*>(ws + WS_ATTN)[tid * 2 + 1] = z;
}

// ---------------- kernel 2: q/k/v GEMV; k,v scattered into cache[pos] ----------------
__global__ void k_qkv(float* __restrict__ ws,
                      const float* __restrict__ qw, const float* __restrict__ qb,
                      const float* __restrict__ kw, const float* __restrict__ kb,
                      const float* __restrict__ vw, const float* __restrict__ vb,
                      float* __restrict__ cacheK, float* __restrict__ cacheV,
                      const int* __restrict__ posp) {
    int wave = threadIdx.x >> 6, lane = threadIdx.x & 63;
    int row = blockIdx.x * 4 + wave;       // 0..6143
    int mat = row >> 11, r = row & (DIMN - 1);
    const float* W = (mat == 0) ? qw : (mat == 1) ? kw : vw;
    const float* B = (mat == 0) ? qb : (mat == 1) ? kb : vb;
    const float4* wrow = reinterpret_cast<const float4*>(W + (size_t)r * DIMN);
    const float4* xv = reinterpret_cast<const float4*>(ws + WS_XN);
    float acc = 0.f;
#pragma unroll
    for (int i = 0; i < 8; ++i) {
        int ch = lane + i * 64;
        acc += dot4(wrow[ch], xv[ch]);
    }
    acc = waveSum(acc);
    if (lane == 0) {
        float y = acc + B[r];
        if (mat == 0) {
            ws[WS_Q + r] = y;
        } else {
            float* dst = (mat == 1) ? cacheK : cacheV;
            dst[(size_t)posp[0] * DIMN + r] = y;
        }
    }
}

// ---------------- kernel 3: scores[t] = dot(K[t], q) / sqrt(d) ----------------
__global__ void k_scores(const float* __restrict__ cacheK, float* __restrict__ ws,
                         const int* __restrict__ posp) {
    int wave = threadIdx.x >> 6, lane = threadIdx.x & 63;
    int t = blockIdx.x * 4 + wave;
    int L = posp[0] + 1;
    if (t >= L) return;
    const float4* krow = reinterpret_cast<const float4*>(cacheK + (size_t)t * DIMN);
    const float4* qv = reinterpret_cast<const float4*>(ws + WS_Q);
    float acc = 0.f;
#pragma unroll
    for (int i = 0; i < 8; ++i) {
        int ch = lane + i * 64;
        acc += dot4(krow[ch], qv[ch]);
    }
    acc = waveSum(acc);
    if (lane == 0) ws[WS_SC + t] = acc * 0.022097086912079608f;  // 1/sqrt(2048)
}

// ---------------- kernel 4: softmax over scores[0..L) ----------------
__global__ void k_softmax(float* __restrict__ ws, const int* __restrict__ posp) {
    __shared__ float red[17];
    int tid = threadIdx.x;  // 1024
    int L = posp[0] + 1;
    int wave = tid >> 6, lane = tid & 63;
    float m = -1e30f;
    for (int i = tid; i < L; i += 1024) m = fmaxf(m, ws[WS_SC + i]);
#pragma unroll
    for (int off = 32; off > 0; off >>= 1) m = fmaxf(m, __shfl_down(m, off, 64));
    if (lane == 0) red[wave] = m;
    __syncthreads();
    if (tid == 0) {
        float mm = red[0];
        for (int i = 1; i < 16; ++i) mm = fmaxf(mm, red[i]);
        red[16] = mm;
    }
    __syncthreads();
    m = red[16];
    float s = 0.f;
    for (int i = tid; i < L; i += 1024) s += expf(ws[WS_SC + i] - m);
    s = waveSum(s);
    __syncthreads();
    if (lane == 0) red[wave] = s;
    __syncthreads();
    if (tid == 0) {
        float t2 = 0.f;
        for (int i = 0; i < 16; ++i) t2 += red[i];
        red[16] = 1.0f / t2;
    }
    __syncthreads();
    float inv = red[16];
    for (int i = tid; i < L; i += 1024) ws[WS_PR + i] = expf(ws[WS_SC + i] - m) * inv;
}

// ---------------- kernel 5: attn[c] += sum_t probs[t] * V[t,c] ----------------
__global__ void k_av(const float* __restrict__ cacheV, float* __restrict__ ws,
                     const int* __restrict__ posp) {
    int L = posp[0] + 1;
    int T = gridDim.y, chunk = blockIdx.y;
    int t0 = (int)((long long)chunk * L / T);
    int t1 = (int)((long long)(chunk + 1) * L / T);
    int c2 = blockIdx.x * 256 + threadIdx.x;  // float-pair column index, 0..1023
    const float2* Vp = reinterpret_cast<const float2*>(cacheV);
    float a0 = 0.f, a1 = 0.f;
    for (int t = t0; t < t1; ++t) {
        float p = ws[WS_PR + t];
        float2 v = Vp[(size_t)t * (DIMN / 2) + c2];
        a0 += p * v.x;
        a1 += p * v.y;
    }
    atomicAdd(&ws[WS_ATTN + 2 * c2], a0);
    atomicAdd(&ws[WS_ATTN + 2 * c2 + 1], a1);
}

// ---------------- kernel 6: x1 = x + attn @ o_w.T + o_b ----------------
__global__ void k_oproj(const float* __restrict__ x, const float* __restrict__ ow,
                        const float* __restrict__ ob, float* __restrict__ ws) {
    int wave = threadIdx.x >> 6, lane = threadIdx.x & 63;
    int r = blockIdx.x * 4 + wave;  // 0..2047
    const float4* wrow = reinterpret_cast<const float4*>(ow + (size_t)r * DIMN);
    const float4* av = reinterpret_cast<const float4*>(ws + WS_ATTN);
    float acc = 0.f;
#pragma unroll
    for (int i = 0; i < 8; ++i) {
        int ch = lane + i * 64;
        acc += dot4(wrow[ch], av[ch]);
    }
    acc = waveSum(acc);
    if (lane == 0) ws[WS_X1 + r] = x[r] + acc + ob[r];
}

// ---------------- kernel 7: hn = rmsnorm(x1)*w ----------------
__global__ void k_rms2(const float* __restrict__ w, float* __restrict__ ws) {
    __shared__ float red[5];
    int tid = threadIdx.x;  // 256
    float4 a = reinterpret_cast<const float4*>(ws + WS_X1)[tid * 2];
    float4 b = reinterpret_cast<const float4*>(ws + WS_X1)[tid * 2 + 1];
    float ss = a.x * a.x + a.y * a.y + a.z * a.z + a.w * a.w +
               b.x * b.x + b.y * b.y + b.z * b.z + b.w * b.w;
    ss = waveSum(ss);
    int wave = tid >> 6, lane = tid & 63;
    if (lane == 0) red[wave] = ss;
    __syncthreads();
    if (tid == 0) red[4] = rsqrtf((red[0] + red[1] + red[2] + red[3]) / (float)DIMN + 1e-6f);
    __syncthreads();
    float scale = red[4];
    float4 wa = reinterpret_cast<const float4*>(w)[tid * 2];
    float4 wb = reinterpret_cast<const float4*>(w)[tid * 2 + 1];
    float4 o0 = make_float4(a.x * scale * wa.x, a.y * scale * wa.y,
                            a.z * scale * wa.z, a.w * scale * wa.w);
    float4 o1 = make_float4(b.x * scale * wb.x, b.y * scale * wb.y,
                            b.z * scale * wb.z, b.w * scale * wb.w);
    reinterpret_cast<float4*>(ws + WS_HN)[tid * 2] = o0;
    reinterpret_cast<float4*>(ws + WS_HN)[tid * 2 + 1] = o1;
}

// ---------------- kernel 8: h = gelu(hn @ fc1_w.T + fc1_b) ----------------
__global__ void k_fc1(const float* __restrict__ w1, const float* __restrict__ b1,
                      float* __restrict__ ws) {
    int wave = threadIdx.x >> 6, lane = threadIdx.x & 63;
    int r = blockIdx.x * 4 + wave;  // 0..8191
    const float4* wrow = reinterpret_cast<const float4*>(w1 + (size_t)r * DIMN);
    const float4* hv = reinterpret_cast<const float4*>(ws + WS_HN);
    float acc = 0.f;
#pragma unroll
    for (int i = 0; i < 8; ++i) {
        int ch = lane + i * 64;
        acc += dot4(wrow[ch], hv[ch]);
    }
    acc = waveSum(acc);
    if (lane == 0) {
        float t = acc + b1[r];
        ws[WS_H + r] = 0.5f * t * (1.0f + erff(t * 0.70710678118654752f));  // exact erf GELU
    }
}

// ---------------- kernel 9: out = x1 + h @ fc2_w.T + fc2_b  (fp32 out) ----------------
__global__ void k_fc2(const float* __restrict__ w2, const float* __restrict__ b2,
                      const float* __restrict__ ws, float* __restrict__ out) {
    int wave = threadIdx.x >> 6, lane = threadIdx.x & 63;
    int r = blockIdx.x * 4 + wave;  // 0..2047
    const float4* wrow = reinterpret_cast<const float4*>(w2 + (size_t)r * HDIM);
    const float4* hv = reinterpret_cast<const float4*>(ws + WS_H);
    float acc = 0.f;
#pragma unroll
    for (int i = 0; i < 32; ++i) {
        int ch = lane + i * 64;
        acc += dot4(wrow[ch], hv[ch]);
    }
    acc = waveSum(acc);
    if (lane == 0) out[r] = ws[WS_X1 + r] + acc + b2[r];
}

extern "C" void kernel_launch(void* const* d_in, const int* in_sizes, int n_in,
                              void* d_out, int out_size, void* d_ws, size_t ws_size,
                              hipStream_t stream) {
    const float* x   = (const float*)d_in[0];
    float* cacheK    = (float*)d_in[1];
    float* cacheV    = (float*)d_in[2];
    const float* anw = (const float*)d_in[3];
    const float* qw  = (const float*)d_in[4];
    const float* qb  = (const float*)d_in[5];
    const float* kw  = (const float*)d_in[6];
    const float* kb  = (const float*)d_in[7];
    const float* vw  = (const float*)d_in[8];
    const float* vb  = (const float*)d_in[9];
    const float* ow  = (const float*)d_in[10];
    const float* ob  = (const float*)d_in[11];
    const float* mnw = (const float*)d_in[12];
    const float* w1  = (const float*)d_in[13];
    const float* b1  = (const float*)d_in[14];
    const float* w2  = (const float*)d_in[15];
    const float* b2  = (const float*)d_in[16];
    const int* posp  = (const int*)d_in[17];
    float* ws = (float*)d_ws;
    float* out = (float*)d_out;

    k_rms1<<<1, 256, 0, stream>>>(x, anw, ws);
    k_qkv<<<1536, 256, 0, stream>>>(ws, qw, qb, kw, kb, vw, vb, cacheK, cacheV, posp);
    k_scores<<<2048, 256, 0, stream>>>(cacheK, ws, posp);
    k_softmax<<<1, 1024, 0, stream>>>(ws, posp);
    k_av<<<dim3(4, 128), 256, 0, stream>>>(cacheV, ws, posp);
    k_oproj<<<512, 256, 0, stream>>>(x, ow, ob, ws);
    k_rms2<<<1, 256, 0, stream>>>(mnw, ws);
    k_fc1<<<2048, 256, 0, stream>>>(w1, b1, ws);
    k_fc2<<<512, 256, 0, stream>>>(w2, b2, ws, out);
}

// Round 4
// 332.449 us; speedup vs baseline: 1.0113x; 1.0113x over previous
//
#include <hip/hip_runtime.h>

#define DIMN 2048
#define HDIM 8192

// ws layout (float offsets)
#define WS_Q    2048     // 2048  q vector
#define WS_ATTN 4096     // 2048  attention output accumulator (fp32, atomics)
#define WS_X1   6144     // 2048  x + attn@o_w.T + o_b
#define WS_H    10240    // 8192  gelu(fc1)
#define WS_SC   18432    // 8192  attention scores

__device__ __forceinline__ float dot4(float4 w, float4 a) {
    return w.x * a.x + w.y * a.y + w.z * a.z + w.w * a.w;
}

__device__ __forceinline__ float waveSum(float v) {
#pragma unroll
    for (int off = 32; off > 0; off >>= 1) v += __shfl_down(v, off, 64);
    return v;  // lane 0 holds the sum
}

// block-level sum over 256 threads (4 waves); red is 4-float LDS scratch
__device__ __forceinline__ float blockSum256(float v, float* red) {
    v = waveSum(v);
    int wave = threadIdx.x >> 6, lane = threadIdx.x & 63;
    if (lane == 0) red[wave] = v;
    __syncthreads();
    float r = red[0] + red[1] + red[2] + red[3];
    __syncthreads();
    return r;
}

__device__ __forceinline__ float blockMax256(float v, float* red) {
#pragma unroll
    for (int off = 32; off > 0; off >>= 1) v = fmaxf(v, __shfl_down(v, off, 64));
    int wave = threadIdx.x >> 6, lane = threadIdx.x & 63;
    if (lane == 0) red[wave] = v;
    __syncthreads();
    float r = fmaxf(fmaxf(red[0], red[1]), fmaxf(red[2], red[3]));
    __syncthreads();
    return r;
}

// ------- kernel 1: per-block redundant rmsnorm(x) -> LDS; q/k/v GEMV -------
__global__ __launch_bounds__(256) void k_qkv(
        const float* __restrict__ x, const float* __restrict__ anw,
        float* __restrict__ ws,
        const float* __restrict__ qw, const float* __restrict__ qb,
        const float* __restrict__ kw, const float* __restrict__ kb,
        const float* __restrict__ vw, const float* __restrict__ vb,
        float* __restrict__ cacheK, float* __restrict__ cacheV,
        const int* __restrict__ posp) {
    __shared__ float xn[DIMN];
    __shared__ float red[4];
    int tid = threadIdx.x, wave = tid >> 6, lane = tid & 63;
    int row = blockIdx.x * 4 + wave;       // 0..6143
    int mat = row >> 11, r = row & (DIMN - 1);
    const float* W = (mat == 0) ? qw : (mat == 1) ? kw : vw;
    const float* B = (mat == 0) ? qb : (mat == 1) ? kb : vb;
    const float4* wrow = reinterpret_cast<const float4*>(W + (size_t)r * DIMN);
    // issue weight-row loads first: latency overlaps the rmsnorm below
    float4 wr[8];
#pragma unroll
    for (int i = 0; i < 8; ++i) wr[i] = wrow[lane + i * 64];
    // redundant per-block rmsnorm (x, anw are L2-hot broadcasts)
    float4 a = reinterpret_cast<const float4*>(x)[tid * 2];
    float4 b = reinterpret_cast<const float4*>(x)[tid * 2 + 1];
    float ss = dot4(a, a) + dot4(b, b);
    ss = blockSum256(ss, red);
    float scale = rsqrtf(ss / (float)DIMN + 1e-6f);
    float4 wa = reinterpret_cast<const float4*>(anw)[tid * 2];
    float4 wb = reinterpret_cast<const float4*>(anw)[tid * 2 + 1];
    reinterpret_cast<float4*>(xn)[tid * 2] =
        make_float4(a.x * scale * wa.x, a.y * scale * wa.y, a.z * scale * wa.z, a.w * scale * wa.w);
    reinterpret_cast<float4*>(xn)[tid * 2 + 1] =
        make_float4(b.x * scale * wb.x, b.y * scale * wb.y, b.z * scale * wb.z, b.w * scale * wb.w);
    // block 0 zeros the fp32 attention accumulator (runs before k_av)
    if (blockIdx.x == 0) {
        float4 z = make_float4(0.f, 0.f, 0.f, 0.f);
        reinterpret_cast<float4*>(ws + WS_ATTN)[tid * 2] = z;
        reinterpret_cast<float4*>(ws + WS_ATTN)[tid * 2 + 1] = z;
    }
    __syncthreads();
    const float4* xv = reinterpret_cast<const float4*>(xn);
    float acc = 0.f;
#pragma unroll
    for (int i = 0; i < 8; ++i) acc += dot4(wr[i], xv[lane + i * 64]);
    acc = waveSum(acc);
    if (lane == 0) {
        float y = acc + B[r];
        if (mat == 0) {
            ws[WS_Q + r] = y;
        } else {
            float* dst = (mat == 1) ? cacheK : cacheV;
            dst[(size_t)posp[0] * DIMN + r] = y;
        }
    }
}

// ------- kernel 2: scores[t] = dot(K[t], q) / sqrt(d) -------
__global__ __launch_bounds__(256) void k_scores(
        const float* __restrict__ cacheK, float* __restrict__ ws,
        const int* __restrict__ posp) {
    int wave = threadIdx.x >> 6, lane = threadIdx.x & 63;
    int t = blockIdx.x * 4 + wave;
    int L = posp[0] + 1;
    if (t >= L) return;
    const float4* krow = reinterpret_cast<const float4*>(cacheK + (size_t)t * DIMN);
    const float4* qv = reinterpret_cast<const float4*>(ws + WS_Q);
    float acc = 0.f;
#pragma unroll
    for (int i = 0; i < 8; ++i) {
        int ch = lane + i * 64;
        acc += dot4(krow[ch], qv[ch]);
    }
    acc = waveSum(acc);
    if (lane == 0) ws[WS_SC + t] = acc * 0.022097086912079608f;  // 1/sqrt(2048)
}

// ------- kernel 3: per-block redundant softmax stats; attn += p_t * V[t,:] -------
__global__ __launch_bounds__(256) void k_av(
        const float* __restrict__ cacheV, float* __restrict__ ws,
        const int* __restrict__ posp) {
    __shared__ float red[4];
    int tid = threadIdx.x;
    int L = posp[0] + 1;
    // block-redundant softmax stats over scores (L2-hot, ~16 KB)
    float m = -1e30f;
    for (int i = tid; i < L; i += 256) m = fmaxf(m, ws[WS_SC + i]);
    m = blockMax256(m, red);
    float s = 0.f;
    for (int i = tid; i < L; i += 256) s += expf(ws[WS_SC + i] - m);
    s = blockSum256(s, red);
    float inv = 1.0f / s;
    // AV over this block's t-chunk, column slice
    int T = gridDim.y, chunk = blockIdx.y;
    int t0 = (int)((long long)chunk * L / T);
    int t1 = (int)((long long)(chunk + 1) * L / T);
    int c2 = blockIdx.x * 256 + tid;  // float-pair column index, 0..1023
    const float2* Vp = reinterpret_cast<const float2*>(cacheV);
    float a0 = 0.f, a1 = 0.f;
    for (int t = t0; t < t1; ++t) {
        float p = expf(ws[WS_SC + t] - m) * inv;
        float2 v = Vp[(size_t)t * (DIMN / 2) + c2];
        a0 += p * v.x;
        a1 += p * v.y;
    }
    atomicAdd(&ws[WS_ATTN + 2 * c2], a0);
    atomicAdd(&ws[WS_ATTN + 2 * c2 + 1], a1);
}

// ------- kernel 4: x1 = x + attn @ o_w.T + o_b -------
__global__ __launch_bounds__(256) void k_oproj(
        const float* __restrict__ x, const float* __restrict__ ow,
        const float* __restrict__ ob, float* __restrict__ ws) {
    int wave = threadIdx.x >> 6, lane = threadIdx.x & 63;
    int r = blockIdx.x * 4 + wave;  // 0..2047
    const float4* wrow = reinterpret_cast<const float4*>(ow + (size_t)r * DIMN);
    const float4* av = reinterpret_cast<const float4*>(ws + WS_ATTN);
    float acc = 0.f;
#pragma unroll
    for (int i = 0; i < 8; ++i) {
        int ch = lane + i * 64;
        acc += dot4(wrow[ch], av[ch]);
    }
    acc = waveSum(acc);
    if (lane == 0) ws[WS_X1 + r] = x[r] + acc + ob[r];
}

// ------- kernel 5: per-block redundant rmsnorm(x1) -> LDS; h = gelu(fc1) -------
__global__ __launch_bounds__(256) void k_fc1(
        const float* __restrict__ w1, const float* __restrict__ b1,
        const float* __restrict__ mnw, float* __restrict__ ws) {
    __shared__ float hn[DIMN];
    __shared__ float red[4];
    int tid = threadIdx.x, wave = tid >> 6, lane = tid & 63;
    int r = blockIdx.x * 4 + wave;  // 0..8191
    const float4* wrow = reinterpret_cast<const float4*>(w1 + (size_t)r * DIMN);
    float4 wr[8];
#pragma unroll
    for (int i = 0; i < 8; ++i) wr[i] = wrow[lane + i * 64];
    // redundant per-block rmsnorm of x1
    float4 a = reinterpret_cast<const float4*>(ws + WS_X1)[tid * 2];
    float4 b = reinterpret_cast<const float4*>(ws + WS_X1)[tid * 2 + 1];
    float ss = dot4(a, a) + dot4(b, b);
    ss = blockSum256(ss, red);
    float scale = rsqrtf(ss / (float)DIMN + 1e-6f);
    float4 wa = reinterpret_cast<const float4*>(mnw)[tid * 2];
    float4 wb = reinterpret_cast<const float4*>(mnw)[tid * 2 + 1];
    reinterpret_cast<float4*>(hn)[tid * 2] =
        make_float4(a.x * scale * wa.x, a.y * scale * wa.y, a.z * scale * wa.z, a.w * scale * wa.w);
    reinterpret_cast<float4*>(hn)[tid * 2 + 1] =
        make_float4(b.x * scale * wb.x, b.y * scale * wb.y, b.z * scale * wb.z, b.w * scale * wb.w);
    __syncthreads();
    const float4* hv = reinterpret_cast<const float4*>(hn);
    float acc = 0.f;
#pragma unroll
    for (int i = 0; i < 8; ++i) acc += dot4(wr[i], hv[lane + i * 64]);
    acc = waveSum(acc);
    if (lane == 0) {
        float t = acc + b1[r];
        ws[WS_H + r] = 0.5f * t * (1.0f + erff(t * 0.70710678118654752f));  // exact erf GELU
    }
}

// ------- kernel 6: out = x1 + h @ fc2_w.T + fc2_b  (fp32 out) -------
__global__ __launch_bounds__(256) void k_fc2(
        const float* __restrict__ w2, const float* __restrict__ b2,
        const float* __restrict__ ws, float* __restrict__ out) {
    int wave = threadIdx.x >> 6, lane = threadIdx.x & 63;
    int r = blockIdx.x * 4 + wave;  // 0..2047
    const float4* wrow = reinterpret_cast<const float4*>(w2 + (size_t)r * HDIM);
    const float4* hv = reinterpret_cast<const float4*>(ws + WS_H);
    float acc = 0.f;
#pragma unroll
    for (int i = 0; i < 32; ++i) {
        int ch = lane + i * 64;
        acc += dot4(wrow[ch], hv[ch]);
    }
    acc = waveSum(acc);
    if (lane == 0) out[r] = ws[WS_X1 + r] + acc + b2[r];
}

extern "C" void kernel_launch(void* const* d_in, const int* in_sizes, int n_in,
                              void* d_out, int out_size, void* d_ws, size_t ws_size,
                              hipStream_t stream) {
    const float* x   = (const float*)d_in[0];
    float* cacheK    = (float*)d_in[1];
    float* cacheV    = (float*)d_in[2];
    const float* anw = (const float*)d_in[3];
    const float* qw  = (const float*)d_in[4];
    const float* qb  = (const float*)d_in[5];
    const float* kw  = (const float*)d_in[6];
    const float* kb  = (const float*)d_in[7];
    const float* vw  = (const float*)d_in[8];
    const float* vb  = (const float*)d_in[9];
    const float* ow  = (const float*)d_in[10];
    const float* ob  = (const float*)d_in[11];
    const float* mnw = (const float*)d_in[12];
    const float* w1  = (const float*)d_in[13];
    const float* b1  = (const float*)d_in[14];
    const float* w2  = (const float*)d_in[15];
    const float* b2  = (const float*)d_in[16];
    const int* posp  = (const int*)d_in[17];
    float* ws = (float*)d_ws;
    float* out = (float*)d_out;

    k_qkv<<<1536, 256, 0, stream>>>(x, anw, ws, qw, qb, kw, kb, vw, vb, cacheK, cacheV, posp);
    k_scores<<<1025, 256, 0, stream>>>(cacheK, ws, posp);
    k_av<<<dim3(4, 128), 256, 0, stream>>>(cacheV, ws, posp);
    k_oproj<<<512, 256, 0, stream>>>(x, ow, ob, ws);
    k_fc1<<<2048, 256, 0, stream>>>(w1, b1, mnw, ws);
    k_fc2<<<512, 256, 0, stream>>>(w2, b2, ws, out);
}